// Round 1
// baseline (3043.420 us; speedup 1.0000x reference)
//
#include <hip/hip_runtime.h>
#include <hip/hip_bf16.h>

#define N_NODES 100000
#define N_EDGES 3200000
#define N_GRAPHS 128
#define FIN 512
#define NCLS 128
#define HID 256
#define OUT_DIM 10
#define BN_EPS 1e-5f

// ---------------- degree / norm ----------------
__global__ void deg_kernel(const int* __restrict__ src, const int* __restrict__ dst,
                           int* __restrict__ odeg, int* __restrict__ ideg) {
    int e = blockIdx.x * 256 + threadIdx.x;
    if (e < N_EDGES) {
        atomicAdd(&odeg[src[e]], 1);
        atomicAdd(&ideg[dst[e]], 1);
    }
}

__global__ void norm_kernel(const int* __restrict__ odeg, const int* __restrict__ ideg,
                            float* __restrict__ nsrc, float* __restrict__ ndst) {
    int n = blockIdx.x * 256 + threadIdx.x;
    if (n < N_NODES) {
        int od = odeg[n], id = ideg[n];
        nsrc[n] = od > 0 ? rsqrtf((float)od) : 0.f;
        ndst[n] = id > 0 ? rsqrtf((float)id) : 0.f;
    }
}

// ---------------- exclusive scan (single block) ----------------
__global__ __launch_bounds__(1024) void scan_kernel(const int* __restrict__ counts,
                                                    int* __restrict__ row_off) {
    __shared__ int warp_sums[16];
    __shared__ int carry_s;
    const int tid = threadIdx.x;
    const int lane = tid & 63;
    const int wid = tid >> 6;
    if (tid == 0) carry_s = 0;
    __syncthreads();
    const int n = N_NODES;
    const int nChunks = (n + 1023) / 1024;
    for (int c = 0; c < nChunks; c++) {
        int i = c * 1024 + tid;
        int v = (i < n) ? counts[i] : 0;
        int x = v;
        #pragma unroll
        for (int off = 1; off < 64; off <<= 1) {
            int y = __shfl_up(x, off, 64);
            if (lane >= off) x += y;
        }
        if (lane == 63) warp_sums[wid] = x;
        __syncthreads();
        if (wid == 0 && lane < 16) {
            int s = warp_sums[lane];
            #pragma unroll
            for (int off = 1; off < 16; off <<= 1) {
                int y = __shfl_up(s, off, 64);
                if (lane >= off) s += y;
            }
            warp_sums[lane] = s;
        }
        __syncthreads();
        int wprefix = (wid > 0) ? warp_sums[wid - 1] : 0;
        int incl = x + wprefix;
        int carry = carry_s;
        if (i < n) row_off[i] = carry + incl - v;
        __syncthreads();
        if (tid == 0) carry_s = carry + warp_sums[15];
        __syncthreads();
    }
    if (tid == 0) row_off[n] = carry_s;
}

__global__ void copy_int_kernel(const int* __restrict__ a, int* __restrict__ b) {
    int i = blockIdx.x * 256 + threadIdx.x;
    if (i < N_NODES) b[i] = a[i];
}

__global__ void fill_kernel(const int* __restrict__ src, const int* __restrict__ dst,
                            int* __restrict__ cursor, int* __restrict__ csr_src) {
    int e = blockIdx.x * 256 + threadIdx.x;
    if (e < N_EDGES) {
        int d = dst[e];
        int pos = atomicAdd(&cursor[d], 1);
        csr_src[pos] = src[e];
    }
}

// ---------------- w_init transpose: wT[k][c] = w[c][k] ----------------
__global__ void transw_kernel(const float* __restrict__ w, float* __restrict__ wT) {
    int i = blockIdx.x * 256 + threadIdx.x;
    if (i < FIN * NCLS) {
        int k = i / NCLS, c = i % NCLS;
        wT[i] = w[c * FIN + k];
    }
}

// ---------------- generic fp32 GEMM: C[M,NN] = A[M,K] @ B[K,NN] ----------------
// epilogue: C = acc * rowscale[m] + bias[n]   (either may be null)
__global__ __launch_bounds__(256) void gemm_kernel(
    const float* __restrict__ A, const float* __restrict__ B, float* __restrict__ C,
    int M, int K, int NN, const float* __restrict__ rowscale, const float* __restrict__ bias)
{
    __shared__ __align__(16) float As[16][68];
    __shared__ __align__(16) float Bs[16][68];
    const int bn0 = blockIdx.x * 64;
    const int bm0 = blockIdx.y * 64;
    const int tid = threadIdx.x;
    const int tm = (tid >> 4) << 2;
    const int tn = (tid & 15) << 2;
    float acc[4][4] = {};
    for (int k0 = 0; k0 < K; k0 += 16) {
        #pragma unroll
        for (int i = 0; i < 4; i++) {
            int idx = tid + i * 256;      // 0..1023
            int m = idx >> 4, k = idx & 15;
            int gm = bm0 + m;
            As[k][m] = (gm < M) ? A[(size_t)gm * K + (k0 + k)] : 0.f;
            int kb = idx >> 6, nb = idx & 63;
            Bs[kb][nb] = B[(size_t)(k0 + kb) * NN + (bn0 + nb)];
        }
        __syncthreads();
        #pragma unroll
        for (int kk = 0; kk < 16; kk++) {
            float a0 = As[kk][tm], a1 = As[kk][tm + 1], a2 = As[kk][tm + 2], a3 = As[kk][tm + 3];
            float b0 = Bs[kk][tn], b1 = Bs[kk][tn + 1], b2 = Bs[kk][tn + 2], b3 = Bs[kk][tn + 3];
            acc[0][0] += a0 * b0; acc[0][1] += a0 * b1; acc[0][2] += a0 * b2; acc[0][3] += a0 * b3;
            acc[1][0] += a1 * b0; acc[1][1] += a1 * b1; acc[1][2] += a1 * b2; acc[1][3] += a1 * b3;
            acc[2][0] += a2 * b0; acc[2][1] += a2 * b1; acc[2][2] += a2 * b2; acc[2][3] += a2 * b3;
            acc[3][0] += a3 * b0; acc[3][1] += a3 * b1; acc[3][2] += a3 * b2; acc[3][3] += a3 * b3;
        }
        __syncthreads();
    }
    #pragma unroll
    for (int i = 0; i < 4; i++) {
        int gm = bm0 + tm + i;
        if (gm >= M) break;
        float rs = rowscale ? rowscale[gm] : 1.f;
        #pragma unroll
        for (int j = 0; j < 4; j++) {
            float v = acc[i][j] * rs;
            if (bias) v += bias[bn0 + tn + j];
            C[(size_t)gm * NN + bn0 + tn + j] = v;
        }
    }
}

// ---------------- aggregation: agg[n,:] = sum over in-edges of hs[src,:] ----------------
template <int D>
__global__ __launch_bounds__(256) void agg_kernel(const float* __restrict__ hs,
                                                  const int* __restrict__ row_off,
                                                  const int* __restrict__ csr_src,
                                                  float* __restrict__ agg)
{
    int wave = (blockIdx.x * 256 + threadIdx.x) >> 6;
    int lane = threadIdx.x & 63;
    if (wave >= N_NODES) return;
    int beg = row_off[wave], end = row_off[wave + 1];
    if constexpr (D == 256) {
        float4 acc = make_float4(0.f, 0.f, 0.f, 0.f);
        const float4* base = reinterpret_cast<const float4*>(hs);
        for (int e = beg; e < end; e++) {
            int s = csr_src[e];
            float4 v = base[(size_t)s * 64 + lane];
            acc.x += v.x; acc.y += v.y; acc.z += v.z; acc.w += v.w;
        }
        reinterpret_cast<float4*>(agg)[(size_t)wave * 64 + lane] = acc;
    } else {
        float2 acc = make_float2(0.f, 0.f);
        const float2* base = reinterpret_cast<const float2*>(hs);
        for (int e = beg; e < end; e++) {
            int s = csr_src[e];
            float2 v = base[(size_t)s * 64 + lane];
            acc.x += v.x; acc.y += v.y;
        }
        reinterpret_cast<float2*>(agg)[(size_t)wave * 64 + lane] = acc;
    }
}

// ---------------- BN stats: per-channel sum and sumsq ----------------
__global__ void stats_kernel(const float* __restrict__ x, float* __restrict__ stats) {
    int c = threadIdx.x;   // 256 channels
    float s = 0.f, q = 0.f;
    for (int r = blockIdx.x; r < N_NODES; r += gridDim.x) {
        float v = x[(size_t)r * HID + c];
        s += v; q += v * v;
    }
    atomicAdd(&stats[c], s);
    atomicAdd(&stats[HID + c], q);
}

// ---------------- BN normalize + ReLU (+ optional row scale for next layer) ----------------
__global__ void bn_kernel(const float* __restrict__ x, float* __restrict__ y,
                          const float* __restrict__ stats,
                          const float* __restrict__ gamma, const float* __restrict__ beta,
                          const float* __restrict__ rowscale)
{
    const float inv_n = 1.f / (float)N_NODES;
    size_t total = (size_t)N_NODES * HID;
    for (size_t idx = (size_t)blockIdx.x * 256 + threadIdx.x; idx < total;
         idx += (size_t)gridDim.x * 256) {
        int c = (int)(idx & (HID - 1));
        size_t r = idx >> 8;
        float mu = stats[c] * inv_n;
        float var = fmaf(-mu, mu, stats[HID + c] * inv_n);
        float v = (x[idx] - mu) * rsqrtf(var + BN_EPS) * gamma[c] + beta[c];
        v = fmaxf(v, 0.f);
        if (rowscale) v *= rowscale[r];
        y[idx] = v;
    }
}

// ---------------- graph start offsets ----------------
__global__ void gstart_kernel(const int* __restrict__ gids, int* __restrict__ gstart) {
    int n = blockIdx.x * 256 + threadIdx.x;
    if (n >= N_NODES) return;
    int g = gids[n];
    int gp = (n == 0) ? -1 : gids[n - 1];
    for (int gg = gp + 1; gg <= g; gg++) gstart[gg] = n;
    if (n == N_NODES - 1) {
        for (int gg = g + 1; gg <= N_GRAPHS; gg++) gstart[gg] = N_NODES;
    }
}

// ---------------- per-graph max over nodes ----------------
__global__ void segmax_kernel(const float* __restrict__ h, const int* __restrict__ gstart,
                              float* __restrict__ hg) {
    int g = blockIdx.x;
    int c = threadIdx.x;
    int beg = gstart[g], end = gstart[g + 1];
    float m = -1e30f;
    for (int n = beg; n < end; n++) m = fmaxf(m, h[(size_t)n * HID + c]);
    hg[g * HID + c] = m;
}

// ---------------- final fc ----------------
__global__ void fc_kernel(const float* __restrict__ hg, const float* __restrict__ w,
                          const float* __restrict__ b, float* __restrict__ out) {
    int idx = blockIdx.x * 256 + threadIdx.x;
    if (idx >= N_GRAPHS * OUT_DIM) return;
    int g = idx / OUT_DIM, j = idx % OUT_DIM;
    float s = b[j];
    for (int c = 0; c < HID; c++) s += hg[g * HID + c] * w[c * OUT_DIM + j];
    out[idx] = s;
}

extern "C" void kernel_launch(void* const* d_in, const int* in_sizes, int n_in,
                              void* d_out, int out_size, void* d_ws, size_t ws_size,
                              hipStream_t stream) {
    const float* h      = (const float*)d_in[0];
    const int*   src    = (const int*)d_in[1];
    const int*   dst    = (const int*)d_in[2];
    const int*   gids   = (const int*)d_in[3];
    const float* w_init = (const float*)d_in[4];
    const float* lw[3]    = { (const float*)d_in[5],  (const float*)d_in[9],  (const float*)d_in[13] };
    const float* lb[3]    = { (const float*)d_in[6],  (const float*)d_in[10], (const float*)d_in[14] };
    const float* gamma[3] = { (const float*)d_in[7],  (const float*)d_in[11], (const float*)d_in[15] };
    const float* beta[3]  = { (const float*)d_in[8],  (const float*)d_in[12], (const float*)d_in[16] };
    const float* fc_w = (const float*)d_in[17];
    const float* fc_b = (const float*)d_in[18];
    float* out = (float*)d_out;

    // ---- workspace layout ----
    char* ws = (char*)d_ws;
    size_t off = 0;
    auto alloc = [&](size_t bytes) { size_t o = off; off += (bytes + 255) & ~(size_t)255; return o; };
    size_t o_bufA  = alloc((size_t)N_NODES * HID * 4);
    size_t o_bufB  = alloc((size_t)N_NODES * HID * 4);
    size_t o_wT    = alloc((size_t)FIN * NCLS * 4);
    size_t o_nsrc  = alloc((size_t)N_NODES * 4);
    size_t o_ndst  = alloc((size_t)N_NODES * 4);
    size_t o_odeg  = alloc((size_t)N_NODES * 4);
    size_t o_ideg  = alloc((size_t)N_NODES * 4);
    size_t o_roff  = alloc((size_t)(N_NODES + 1) * 4);
    size_t o_cur   = alloc((size_t)N_NODES * 4);
    size_t o_csr   = alloc((size_t)N_EDGES * 4);
    size_t o_stats = alloc((size_t)2 * HID * 4);
    size_t o_gst   = alloc((size_t)(N_GRAPHS + 1) * 4);
    size_t o_hg    = alloc((size_t)N_GRAPHS * HID * 4);
    if (off > ws_size) return;  // workspace too small: fail loudly via validation

    float* bufA = (float*)(ws + o_bufA);
    float* bufB = (float*)(ws + o_bufB);
    float* wT   = (float*)(ws + o_wT);
    float* nsrc = (float*)(ws + o_nsrc);
    float* ndst = (float*)(ws + o_ndst);
    int*   odeg = (int*)(ws + o_odeg);
    int*   ideg = (int*)(ws + o_ideg);
    int*   roff = (int*)(ws + o_roff);
    int*   cur  = (int*)(ws + o_cur);
    int*   csr  = (int*)(ws + o_csr);
    float* stats= (float*)(ws + o_stats);
    int*   gst  = (int*)(ws + o_gst);
    float* hg   = (float*)(ws + o_hg);

    const int eb = (N_EDGES + 255) / 256;   // 12500
    const int nb = (N_NODES + 255) / 256;   // 391

    // degrees + norms
    hipMemsetAsync(odeg, 0, (size_t)N_NODES * 4, stream);
    hipMemsetAsync(ideg, 0, (size_t)N_NODES * 4, stream);
    deg_kernel<<<eb, 256, 0, stream>>>(src, dst, odeg, ideg);
    norm_kernel<<<nb, 256, 0, stream>>>(odeg, ideg, nsrc, ndst);

    // CSR by dst
    scan_kernel<<<1, 1024, 0, stream>>>(ideg, roff);
    copy_int_kernel<<<nb, 256, 0, stream>>>(roff, cur);
    fill_kernel<<<eb, 256, 0, stream>>>(src, dst, cur, csr);

    // graph segment starts
    gstart_kernel<<<nb, 256, 0, stream>>>(gids, gst);

    // wT = w_init^T
    transw_kernel<<<(FIN * NCLS + 255) / 256, 256, 0, stream>>>(w_init, wT);

    // h0s = (h @ wT) * nsrc   -> bufA [N,128]
    {
        dim3 grid(NCLS / 64, (N_NODES + 63) / 64);
        gemm_kernel<<<grid, 256, 0, stream>>>(h, wT, bufA, N_NODES, FIN, NCLS, nsrc, nullptr);
    }

    const int aggb = (N_NODES * 64 + 255) / 256;  // one wave per node
    float* cin  = bufA;  // scaled input to aggregation
    float* cout = bufB;

    for (int l = 0; l < 3; l++) {
        int d_in_l = (l == 0) ? NCLS : HID;
        // agg: cin -> cout  [N, d_in_l]
        if (d_in_l == 128)
            agg_kernel<128><<<aggb, 256, 0, stream>>>(cin, roff, csr, cout);
        else
            agg_kernel<256><<<aggb, 256, 0, stream>>>(cin, roff, csr, cout);
        // pre = (agg * ndst) @ lw + lb  : cout -> cin  [N, 256]
        {
            dim3 grid(HID / 64, (N_NODES + 63) / 64);
            gemm_kernel<<<grid, 256, 0, stream>>>(cout, lw[l], cin, N_NODES, d_in_l, HID, ndst, lb[l]);
        }
        // BN stats + normalize (+ scale by nsrc for layers 0,1): cin -> cout
        hipMemsetAsync(stats, 0, 2 * HID * 4, stream);
        stats_kernel<<<512, 256, 0, stream>>>(cin, stats);
        bn_kernel<<<2048, 256, 0, stream>>>(cin, cout, stats, gamma[l], beta[l],
                                            (l < 2) ? nsrc : nullptr);
        // next layer reads cout; keep ping-pong roles (cin/cout swap happens naturally:
        // aggregation next reads cout and writes cin)
        float* t = cin; cin = cout; cout = t;
    }

    // cin now holds final BN output [N, 256]
    segmax_kernel<<<N_GRAPHS, 256, 0, stream>>>(cin, gst, hg);
    fc_kernel<<<(N_GRAPHS * OUT_DIM + 255) / 256, 256, 0, stream>>>(hg, fc_w, fc_b, out);
}

// Round 2
// 2048.541 us; speedup vs baseline: 1.4857x; 1.4857x over previous
//
#include <hip/hip_runtime.h>
#include <hip/hip_bf16.h>

#define N_NODES 100000
#define N_EDGES 3200000
#define N_GRAPHS 128
#define FIN 512
#define NCLS 128
#define HID 256
#define OUT_DIM 10
#define BN_EPS 1e-5f

typedef unsigned short ush;
typedef ush su16x8 __attribute__((ext_vector_type(8)));
typedef ush su16x4 __attribute__((ext_vector_type(4)));
typedef ush su16x2 __attribute__((ext_vector_type(2)));
typedef __bf16 bf16x8v __attribute__((ext_vector_type(8)));
typedef float f32x4v __attribute__((ext_vector_type(4)));

__device__ __forceinline__ float bf2f(ush u) {
    union { unsigned int i; float f; } v; v.i = ((unsigned int)u) << 16; return v.f;
}
__device__ __forceinline__ ush f2bf(float f) {
    union { float f; unsigned int i; } v; v.f = f;
    unsigned int r = v.i + 0x7FFFu + ((v.i >> 16) & 1u);
    return (ush)(r >> 16);
}

// MFMA shim: works whether the gfx950 builtin takes 16-bit-int vectors or __bf16 vectors.
template <typename T>
__device__ __forceinline__ auto mfma_sel(T a, T b, f32x4v c, int)
    -> decltype(__builtin_amdgcn_mfma_f32_16x16x32_bf16(a, b, c, 0, 0, 0)) {
    return __builtin_amdgcn_mfma_f32_16x16x32_bf16(a, b, c, 0, 0, 0);
}
template <typename T>
__device__ __forceinline__ f32x4v mfma_sel(T a, T b, f32x4v c, long) {
    return __builtin_amdgcn_mfma_f32_16x16x32_bf16(
        __builtin_bit_cast(bf16x8v, a), __builtin_bit_cast(bf16x8v, b), c, 0, 0, 0);
}
__device__ __forceinline__ f32x4v MFMA_BF16(su16x8 a, su16x8 b, f32x4v c) {
    return mfma_sel(a, b, c, 0);
}

// ---------------- degree / norm ----------------
__global__ void deg_kernel(const int* __restrict__ src, const int* __restrict__ dst,
                           int* __restrict__ odeg, int* __restrict__ ideg) {
    int e = blockIdx.x * 256 + threadIdx.x;
    if (e < N_EDGES) {
        atomicAdd(&odeg[src[e]], 1);
        atomicAdd(&ideg[dst[e]], 1);
    }
}

__global__ void norm_kernel(const int* __restrict__ odeg, const int* __restrict__ ideg,
                            float* __restrict__ nsrc, float* __restrict__ ndst) {
    int n = blockIdx.x * 256 + threadIdx.x;
    if (n < N_NODES) {
        int od = odeg[n], id = ideg[n];
        nsrc[n] = od > 0 ? rsqrtf((float)od) : 0.f;
        ndst[n] = id > 0 ? rsqrtf((float)id) : 0.f;
    }
}

// ---------------- exclusive scan (single block) ----------------
__global__ __launch_bounds__(1024) void scan_kernel(const int* __restrict__ counts,
                                                    int* __restrict__ row_off) {
    __shared__ int warp_sums[16];
    __shared__ int carry_s;
    const int tid = threadIdx.x;
    const int lane = tid & 63;
    const int wid = tid >> 6;
    if (tid == 0) carry_s = 0;
    __syncthreads();
    const int n = N_NODES;
    const int nChunks = (n + 1023) / 1024;
    for (int c = 0; c < nChunks; c++) {
        int i = c * 1024 + tid;
        int v = (i < n) ? counts[i] : 0;
        int x = v;
        #pragma unroll
        for (int off = 1; off < 64; off <<= 1) {
            int y = __shfl_up(x, off, 64);
            if (lane >= off) x += y;
        }
        if (lane == 63) warp_sums[wid] = x;
        __syncthreads();
        if (wid == 0 && lane < 16) {
            int s = warp_sums[lane];
            #pragma unroll
            for (int off = 1; off < 16; off <<= 1) {
                int y = __shfl_up(s, off, 64);
                if (lane >= off) s += y;
            }
            warp_sums[lane] = s;
        }
        __syncthreads();
        int wprefix = (wid > 0) ? warp_sums[wid - 1] : 0;
        int incl = x + wprefix;
        int carry = carry_s;
        if (i < n) row_off[i] = carry + incl - v;
        __syncthreads();
        if (tid == 0) carry_s = carry + warp_sums[15];
        __syncthreads();
    }
    if (tid == 0) row_off[n] = carry_s;
}

__global__ void copy_int_kernel(const int* __restrict__ a, int* __restrict__ b) {
    int i = blockIdx.x * 256 + threadIdx.x;
    if (i < N_NODES) b[i] = a[i];
}

__global__ void fill_kernel(const int* __restrict__ src, const int* __restrict__ dst,
                            int* __restrict__ cursor, int* __restrict__ csr_src) {
    int e = blockIdx.x * 256 + threadIdx.x;
    if (e < N_EDGES) {
        int d = dst[e];
        int pos = atomicAdd(&cursor[d], 1);
        csr_src[pos] = src[e];
    }
}

// ---------------- weight prep ----------------
// GEMM-0 wants B^T = w_init itself [NC][FIN]; just convert f32->bf16.
__global__ void cvt_w0_kernel(const float* __restrict__ w, ush* __restrict__ o) {
    int i = blockIdx.x * 256 + threadIdx.x;
    if (i < NCLS * FIN) o[i] = f2bf(w[i]);
}
// lw [K][HID] -> o [HID][K] bf16 (B^T)
__global__ void cvt_lwT_kernel(const float* __restrict__ lw, ush* __restrict__ o, int K) {
    int i = blockIdx.x * 256 + threadIdx.x;
    if (i < K * HID) {
        int n = i / K, k = i % K;
        o[i] = f2bf(lw[(size_t)k * HID + n]);
    }
}

// ---------------- MFMA GEMM: C[M,NN](bf16) = A[M,K] @ BT[NN,K]^T ----------------
// epilogue: C = acc * rowscale[m] + bias[n]
template <bool A_F32>
__global__ __launch_bounds__(256) void mfma_gemm(
    const void* __restrict__ Aptr, const ush* __restrict__ BT,
    ush* __restrict__ C, int M, int K, int NN,
    const float* __restrict__ rowscale, const float* __restrict__ bias)
{
    __shared__ __align__(16) ush As[128][40];   // 32 used + pad; 80B row stride
    __shared__ __align__(16) ush Bs[128][40];
    const int bn0 = blockIdx.x * 128;
    const int bm0 = blockIdx.y * 128;
    const int tid = threadIdx.x;
    const int lane = tid & 63;
    const int wv = tid >> 6;          // 4 waves: 2x2 of 64x64
    const int wm = (wv >> 1) * 64;
    const int wn = (wv & 1) * 64;
    const int lm = lane & 15;
    const int lg = lane >> 4;

    f32x4v zero = {0.f, 0.f, 0.f, 0.f};
    f32x4v acc[4][4];
    #pragma unroll
    for (int mi = 0; mi < 4; mi++)
        #pragma unroll
        for (int ni = 0; ni < 4; ni++) acc[mi][ni] = zero;

    for (int k0 = 0; k0 < K; k0 += 32) {
        // stage B^T tile [128 n][32 k]
        #pragma unroll
        for (int i = 0; i < 2; i++) {
            int seg = tid + i * 256;           // 0..511
            int n = seg >> 2, kp = seg & 3;
            su16x8 v = *(const su16x8*)&BT[(size_t)(bn0 + n) * K + k0 + kp * 8];
            *(su16x8*)&Bs[n][kp * 8] = v;
        }
        if constexpr (A_F32) {
            const float* Af = (const float*)Aptr;
            #pragma unroll
            for (int i = 0; i < 4; i++) {
                int seg = tid + i * 256;       // 0..1023
                int m = seg >> 3, kp = seg & 7;
                int gm = bm0 + m; if (gm >= M) gm = M - 1;
                float4 v = *(const float4*)&Af[(size_t)gm * K + k0 + kp * 4];
                su16x4 o = { f2bf(v.x), f2bf(v.y), f2bf(v.z), f2bf(v.w) };
                *(su16x4*)&As[m][kp * 4] = o;
            }
        } else {
            const ush* Ab = (const ush*)Aptr;
            #pragma unroll
            for (int i = 0; i < 2; i++) {
                int seg = tid + i * 256;
                int m = seg >> 2, kp = seg & 3;
                int gm = bm0 + m; if (gm >= M) gm = M - 1;
                su16x8 v = *(const su16x8*)&Ab[(size_t)gm * K + k0 + kp * 8];
                *(su16x8*)&As[m][kp * 8] = v;
            }
        }
        __syncthreads();
        su16x8 af[4], bfr[4];
        #pragma unroll
        for (int i = 0; i < 4; i++)
            af[i] = *(const su16x8*)&As[wm + i * 16 + lm][lg * 8];
        #pragma unroll
        for (int i = 0; i < 4; i++)
            bfr[i] = *(const su16x8*)&Bs[wn + i * 16 + lm][lg * 8];
        #pragma unroll
        for (int mi = 0; mi < 4; mi++)
            #pragma unroll
            for (int ni = 0; ni < 4; ni++)
                acc[mi][ni] = MFMA_BF16(af[mi], bfr[ni], acc[mi][ni]);
        __syncthreads();
    }

    #pragma unroll
    for (int mi = 0; mi < 4; mi++) {
        #pragma unroll
        for (int j = 0; j < 4; j++) {
            int gm = bm0 + wm + mi * 16 + lg * 4 + j;
            if (gm >= M) continue;
            float rs = rowscale ? rowscale[gm] : 1.f;
            #pragma unroll
            for (int ni = 0; ni < 4; ni++) {
                int gn = bn0 + wn + ni * 16 + lm;
                float v = acc[mi][ni][j] * rs;
                if (bias) v += bias[gn];
                C[(size_t)gm * NN + gn] = f2bf(v);
            }
        }
    }
}

// ---------------- aggregation (bf16): agg[n,:] = sum_{e in CSR[n]} hs[src_e,:] ----------------
template <int D>
__global__ __launch_bounds__(256) void agg_bf16(const ush* __restrict__ hs,
                                                const int* __restrict__ roff,
                                                const int* __restrict__ csr,
                                                ush* __restrict__ out)
{
    int node = (blockIdx.x * 256 + threadIdx.x) >> 6;
    int lane = threadIdx.x & 63;
    if (node >= N_NODES) return;
    int beg = roff[node], end = roff[node + 1];
    if constexpr (D == 256) {
        float a0 = 0.f, a1 = 0.f, a2 = 0.f, a3 = 0.f;
        for (int e = beg; e < end; e++) {
            int s = csr[e];
            su16x4 v = *(const su16x4*)&hs[(size_t)s * 256 + lane * 4];
            a0 += bf2f(v[0]); a1 += bf2f(v[1]); a2 += bf2f(v[2]); a3 += bf2f(v[3]);
        }
        su16x4 o = { f2bf(a0), f2bf(a1), f2bf(a2), f2bf(a3) };
        *(su16x4*)&out[(size_t)node * 256 + lane * 4] = o;
    } else {
        float a0 = 0.f, a1 = 0.f;
        for (int e = beg; e < end; e++) {
            int s = csr[e];
            su16x2 v = *(const su16x2*)&hs[(size_t)s * 128 + lane * 2];
            a0 += bf2f(v[0]); a1 += bf2f(v[1]);
        }
        su16x2 o = { f2bf(a0), f2bf(a1) };
        *(su16x2*)&out[(size_t)node * 128 + lane * 2] = o;
    }
}

// ---------------- BN stats (bf16 input) ----------------
__global__ void stats_bf16(const ush* __restrict__ x, float* __restrict__ stats) {
    int c = threadIdx.x;   // 256 channels
    float s = 0.f, q = 0.f;
    for (int r = blockIdx.x; r < N_NODES; r += gridDim.x) {
        float v = bf2f(x[(size_t)r * HID + c]);
        s += v; q += v * v;
    }
    atomicAdd(&stats[c], s);
    atomicAdd(&stats[HID + c], q);
}

// ---------------- BN normalize + ReLU (+ optional nsrc row scale), bf16->bf16 ----------------
__global__ void bn_bf16(const ush* __restrict__ x, ush* __restrict__ y,
                        const float* __restrict__ stats,
                        const float* __restrict__ gamma, const float* __restrict__ beta,
                        const float* __restrict__ rowscale)
{
    const float inv_n = 1.f / (float)N_NODES;
    const int nchunk = N_NODES * (HID / 8);
    for (int idx = blockIdx.x * 256 + threadIdx.x; idx < nchunk; idx += gridDim.x * 256) {
        int r = idx >> 5;            // 32 chunks per row
        int c0 = (idx & 31) * 8;
        su16x8 v = *(const su16x8*)&x[(size_t)r * HID + c0];
        float rs = rowscale ? rowscale[r] : 1.f;
        su16x8 o;
        #pragma unroll
        for (int j = 0; j < 8; j++) {
            int c = c0 + j;
            float mu = stats[c] * inv_n;
            float var = fmaf(-mu, mu, stats[HID + c] * inv_n);
            float vv = (bf2f(v[j]) - mu) * rsqrtf(var + BN_EPS) * gamma[c] + beta[c];
            vv = fmaxf(vv, 0.f) * rs;
            o[j] = f2bf(vv);
        }
        *(su16x8*)&y[(size_t)r * HID + c0] = o;
    }
}

// ---------------- graph start offsets ----------------
__global__ void gstart_kernel(const int* __restrict__ gids, int* __restrict__ gstart) {
    int n = blockIdx.x * 256 + threadIdx.x;
    if (n >= N_NODES) return;
    int g = gids[n];
    int gp = (n == 0) ? -1 : gids[n - 1];
    for (int gg = gp + 1; gg <= g; gg++) gstart[gg] = n;
    if (n == N_NODES - 1) {
        for (int gg = g + 1; gg <= N_GRAPHS; gg++) gstart[gg] = N_NODES;
    }
}

// ---------------- per-graph max (values >= 0 post-ReLU; hg pre-zeroed) ----------------
__global__ void segmax_bf16(const ush* __restrict__ h, const int* __restrict__ gstart,
                            float* __restrict__ hg) {
    int g = blockIdx.x;
    int chunk = blockIdx.y;                 // 8 chunks per graph
    int c = threadIdx.x;                    // channel
    int beg = gstart[g], end = gstart[g + 1];
    int len = end - beg;
    int per = (len + 7) >> 3;
    int s = beg + chunk * per;
    int e = s + per; if (e > end) e = end;
    float m = 0.f;
    for (int n = s; n < e; n++) m = fmaxf(m, bf2f(h[(size_t)n * HID + c]));
    atomicMax((int*)&hg[g * HID + c], __float_as_int(m));
}

// ---------------- final fc ----------------
__global__ void fc_kernel(const float* __restrict__ hg, const float* __restrict__ w,
                          const float* __restrict__ b, float* __restrict__ out) {
    int idx = blockIdx.x * 256 + threadIdx.x;
    if (idx >= N_GRAPHS * OUT_DIM) return;
    int g = idx / OUT_DIM, j = idx % OUT_DIM;
    float s = b[j];
    for (int c = 0; c < HID; c++) s += hg[g * HID + c] * w[c * OUT_DIM + j];
    out[idx] = s;
}

extern "C" void kernel_launch(void* const* d_in, const int* in_sizes, int n_in,
                              void* d_out, int out_size, void* d_ws, size_t ws_size,
                              hipStream_t stream) {
    const float* h      = (const float*)d_in[0];
    const int*   src    = (const int*)d_in[1];
    const int*   dst    = (const int*)d_in[2];
    const int*   gids   = (const int*)d_in[3];
    const float* w_init = (const float*)d_in[4];
    const float* lw[3]    = { (const float*)d_in[5],  (const float*)d_in[9],  (const float*)d_in[13] };
    const float* lb[3]    = { (const float*)d_in[6],  (const float*)d_in[10], (const float*)d_in[14] };
    const float* gamma[3] = { (const float*)d_in[7],  (const float*)d_in[11], (const float*)d_in[15] };
    const float* beta[3]  = { (const float*)d_in[8],  (const float*)d_in[12], (const float*)d_in[16] };
    const float* fc_w = (const float*)d_in[17];
    const float* fc_b = (const float*)d_in[18];
    float* out = (float*)d_out;

    // ---- workspace layout ----
    char* ws = (char*)d_ws;
    size_t off = 0;
    auto alloc = [&](size_t bytes) { size_t o = off; off += (bytes + 255) & ~(size_t)255; return o; };
    size_t o_bufA  = alloc((size_t)N_NODES * HID * 2);       // bf16 [N,256]
    size_t o_bufB  = alloc((size_t)N_NODES * HID * 2);
    size_t o_wB0   = alloc((size_t)NCLS * FIN * 2);          // bf16 [128][512]
    size_t o_lwT0  = alloc((size_t)HID * NCLS * 2);          // bf16 [256][128]
    size_t o_lwT1  = alloc((size_t)HID * HID * 2);
    size_t o_lwT2  = alloc((size_t)HID * HID * 2);
    size_t o_nsrc  = alloc((size_t)N_NODES * 4);
    size_t o_ndst  = alloc((size_t)N_NODES * 4);
    size_t o_odeg  = alloc((size_t)N_NODES * 4);
    size_t o_ideg  = alloc((size_t)N_NODES * 4);
    size_t o_roff  = alloc((size_t)(N_NODES + 1) * 4);
    size_t o_cur   = alloc((size_t)N_NODES * 4);
    size_t o_csr   = alloc((size_t)N_EDGES * 4);
    size_t o_stats = alloc((size_t)2 * HID * 4);
    size_t o_gst   = alloc((size_t)(N_GRAPHS + 1) * 4);
    size_t o_hg    = alloc((size_t)N_GRAPHS * HID * 4);
    if (off > ws_size) return;

    ush*   bufA = (ush*)(ws + o_bufA);
    ush*   bufB = (ush*)(ws + o_bufB);
    ush*   wB0  = (ush*)(ws + o_wB0);
    ush*   lwT[3] = { (ush*)(ws + o_lwT0), (ush*)(ws + o_lwT1), (ush*)(ws + o_lwT2) };
    float* nsrc = (float*)(ws + o_nsrc);
    float* ndst = (float*)(ws + o_ndst);
    int*   odeg = (int*)(ws + o_odeg);
    int*   ideg = (int*)(ws + o_ideg);
    int*   roff = (int*)(ws + o_roff);
    int*   cur  = (int*)(ws + o_cur);
    int*   csr  = (int*)(ws + o_csr);
    float* stats= (float*)(ws + o_stats);
    int*   gst  = (int*)(ws + o_gst);
    float* hg   = (float*)(ws + o_hg);

    const int eb = (N_EDGES + 255) / 256;
    const int nb = (N_NODES + 255) / 256;

    // degrees + norms
    hipMemsetAsync(odeg, 0, (size_t)N_NODES * 4, stream);
    hipMemsetAsync(ideg, 0, (size_t)N_NODES * 4, stream);
    deg_kernel<<<eb, 256, 0, stream>>>(src, dst, odeg, ideg);
    norm_kernel<<<nb, 256, 0, stream>>>(odeg, ideg, nsrc, ndst);

    // CSR by dst
    scan_kernel<<<1, 1024, 0, stream>>>(ideg, roff);
    copy_int_kernel<<<nb, 256, 0, stream>>>(roff, cur);
    fill_kernel<<<eb, 256, 0, stream>>>(src, dst, cur, csr);

    // graph segment starts
    gstart_kernel<<<nb, 256, 0, stream>>>(gids, gst);

    // weight prep
    cvt_w0_kernel<<<(NCLS * FIN + 255) / 256, 256, 0, stream>>>(w_init, wB0);
    cvt_lwT_kernel<<<(NCLS * HID + 255) / 256, 256, 0, stream>>>(lw[0], lwT[0], NCLS);
    cvt_lwT_kernel<<<(HID * HID + 255) / 256, 256, 0, stream>>>(lw[1], lwT[1], HID);
    cvt_lwT_kernel<<<(HID * HID + 255) / 256, 256, 0, stream>>>(lw[2], lwT[2], HID);

    const int mblocks = (N_NODES + 127) / 128;   // 782

    // h0s = (h @ w_init^T) * nsrc -> bufA bf16 [N,128]
    {
        dim3 grid(NCLS / 128, mblocks);
        mfma_gemm<true><<<grid, 256, 0, stream>>>(h, wB0, bufA, N_NODES, FIN, NCLS, nsrc, nullptr);
    }

    const int aggb = (N_NODES * 64 + 255) / 256;  // one wave per node
    ush* cin  = bufA;
    ush* cout = bufB;

    for (int l = 0; l < 3; l++) {
        int din = (l == 0) ? NCLS : HID;
        if (din == 128)
            agg_bf16<128><<<aggb, 256, 0, stream>>>(cin, roff, csr, cout);
        else
            agg_bf16<256><<<aggb, 256, 0, stream>>>(cin, roff, csr, cout);
        {
            dim3 grid(HID / 128, mblocks);
            mfma_gemm<false><<<grid, 256, 0, stream>>>(cout, lwT[l], cin, N_NODES, din, HID,
                                                       ndst, lb[l]);
        }
        hipMemsetAsync(stats, 0, 2 * HID * 4, stream);
        stats_bf16<<<512, 256, 0, stream>>>(cin, stats);
        bn_bf16<<<2048, 256, 0, stream>>>(cin, cout, stats, gamma[l], beta[l],
                                          (l < 2) ? nsrc : nullptr);
        ush* t = cin; cin = cout; cout = t;
    }

    // per-graph max + fc
    hipMemsetAsync(hg, 0, (size_t)N_GRAPHS * HID * 4, stream);
    {
        dim3 grid(N_GRAPHS, 8);
        segmax_bf16<<<grid, 256, 0, stream>>>(cin, gst, hg);
    }
    fc_kernel<<<(N_GRAPHS * OUT_DIM + 255) / 256, 256, 0, stream>>>(hg, fc_w, fc_b, out);
}

// Round 3
// 1462.292 us; speedup vs baseline: 2.0813x; 1.4009x over previous
//
#include <hip/hip_runtime.h>
#include <hip/hip_bf16.h>

#define N_NODES 100000
#define N_EDGES 3200000
#define N_GRAPHS 128
#define FIN 512
#define NCLS 128
#define HID 256
#define OUT_DIM 10
#define BN_EPS 1e-5f

typedef unsigned short ush;
typedef ush su16x8 __attribute__((ext_vector_type(8)));
typedef ush su16x4 __attribute__((ext_vector_type(4)));
typedef __bf16 bf16x8v __attribute__((ext_vector_type(8)));
typedef float f32x4v __attribute__((ext_vector_type(4)));

__device__ __forceinline__ float bf2f(ush u) {
    union { unsigned int i; float f; } v; v.i = ((unsigned int)u) << 16; return v.f;
}
__device__ __forceinline__ ush f2bf(float f) {
    union { float f; unsigned int i; } v; v.f = f;
    unsigned int r = v.i + 0x7FFFu + ((v.i >> 16) & 1u);
    return (ush)(r >> 16);
}

// MFMA shim: works whether the gfx950 builtin takes 16-bit-int vectors or __bf16 vectors.
template <typename T>
__device__ __forceinline__ auto mfma_sel(T a, T b, f32x4v c, int)
    -> decltype(__builtin_amdgcn_mfma_f32_16x16x32_bf16(a, b, c, 0, 0, 0)) {
    return __builtin_amdgcn_mfma_f32_16x16x32_bf16(a, b, c, 0, 0, 0);
}
template <typename T>
__device__ __forceinline__ f32x4v mfma_sel(T a, T b, f32x4v c, long) {
    return __builtin_amdgcn_mfma_f32_16x16x32_bf16(
        __builtin_bit_cast(bf16x8v, a), __builtin_bit_cast(bf16x8v, b), c, 0, 0, 0);
}
__device__ __forceinline__ f32x4v MFMA_BF16(su16x8 a, su16x8 b, f32x4v c) {
    return mfma_sel(a, b, c, 0);
}

// ---------------- degree / norm ----------------
__global__ void deg_kernel(const int* __restrict__ src, const int* __restrict__ dst,
                           int* __restrict__ odeg, int* __restrict__ ideg) {
    int e = blockIdx.x * 256 + threadIdx.x;
    if (e < N_EDGES) {
        atomicAdd(&odeg[src[e]], 1);
        atomicAdd(&ideg[dst[e]], 1);
    }
}

__global__ void norm_kernel(const int* __restrict__ odeg, const int* __restrict__ ideg,
                            float* __restrict__ nsrc, float* __restrict__ ndst) {
    int n = blockIdx.x * 256 + threadIdx.x;
    if (n < N_NODES) {
        int od = odeg[n], id = ideg[n];
        nsrc[n] = od > 0 ? rsqrtf((float)od) : 0.f;
        ndst[n] = id > 0 ? rsqrtf((float)id) : 0.f;
    }
}

// ---------------- 3-phase parallel exclusive scan of ideg -> roff, cur ----------------
#define SCAN_BLOCKS ((N_NODES + 255) / 256)   // 391

__global__ void scan1_kernel(const int* __restrict__ counts, int* __restrict__ bsum) {
    __shared__ int ws[4];
    int i = blockIdx.x * 256 + threadIdx.x;
    int v = (i < N_NODES) ? counts[i] : 0;
    int lane = threadIdx.x & 63, wid = threadIdx.x >> 6;
    int x = v;
    #pragma unroll
    for (int off = 1; off < 64; off <<= 1) { int y = __shfl_up(x, off, 64); if (lane >= off) x += y; }
    if (lane == 63) ws[wid] = x;
    __syncthreads();
    if (threadIdx.x == 0) bsum[blockIdx.x] = ws[0] + ws[1] + ws[2] + ws[3];
}

__global__ __launch_bounds__(512) void scan2_kernel(const int* __restrict__ bsum,
                                                    int* __restrict__ boff) {
    __shared__ int ws[8];
    int tid = threadIdx.x;
    int lane = tid & 63, wid = tid >> 6;
    int v = (tid < SCAN_BLOCKS) ? bsum[tid] : 0;
    int x = v;
    #pragma unroll
    for (int off = 1; off < 64; off <<= 1) { int y = __shfl_up(x, off, 64); if (lane >= off) x += y; }
    if (lane == 63) ws[wid] = x;
    __syncthreads();
    if (wid == 0 && lane < 8) {
        int s = ws[lane];
        #pragma unroll
        for (int off = 1; off < 8; off <<= 1) { int y = __shfl_up(s, off, 64); if (lane >= off) s += y; }
        ws[lane] = s;
    }
    __syncthreads();
    int excl = x - v + (wid > 0 ? ws[wid - 1] : 0);
    if (tid < SCAN_BLOCKS) boff[tid] = excl;
}

__global__ void scan3_kernel(const int* __restrict__ counts, const int* __restrict__ boff,
                             int* __restrict__ roff, int* __restrict__ cur) {
    __shared__ int ws[4];
    int i = blockIdx.x * 256 + threadIdx.x;
    int v = (i < N_NODES) ? counts[i] : 0;
    int lane = threadIdx.x & 63, wid = threadIdx.x >> 6;
    int x = v;
    #pragma unroll
    for (int off = 1; off < 64; off <<= 1) { int y = __shfl_up(x, off, 64); if (lane >= off) x += y; }
    if (lane == 63) ws[wid] = x;
    __syncthreads();
    int wpre = 0;
    #pragma unroll
    for (int w = 0; w < 4; w++) if (w < wid) wpre += ws[w];
    int excl = x - v + wpre + boff[blockIdx.x];
    if (i < N_NODES) { roff[i] = excl; cur[i] = excl; }
    if (i == 0) roff[N_NODES] = N_EDGES;
}

__global__ void fill_kernel(const int* __restrict__ src, const int* __restrict__ dst,
                            int* __restrict__ cursor, int* __restrict__ csr_src) {
    int e = blockIdx.x * 256 + threadIdx.x;
    if (e < N_EDGES) {
        int d = dst[e];
        int pos = atomicAdd(&cursor[d], 1);
        csr_src[pos] = src[e];
    }
}

// ---------------- weight prep ----------------
__global__ void cvt_w0_kernel(const float* __restrict__ w, ush* __restrict__ o) {
    int i = blockIdx.x * 256 + threadIdx.x;
    if (i < NCLS * FIN) o[i] = f2bf(w[i]);
}
// lw [K][HID] -> o [HID][K] bf16 (B^T)
__global__ void cvt_lwT_kernel(const float* __restrict__ lw, ush* __restrict__ o, int K) {
    int i = blockIdx.x * 256 + threadIdx.x;
    if (i < K * HID) {
        int n = i / K, k = i % K;
        o[i] = f2bf(lw[(size_t)k * HID + n]);
    }
}

// ---------------- MFMA GEMM: C[M,NN](bf16) = A[M,K] @ BT[NN,K]^T ----------------
// epilogue: C = acc * rowscale[m] + bias[n]; optional per-channel sum/sumsq atomics.
template <bool A_F32, bool DO_STATS>
__global__ __launch_bounds__(256) void mfma_gemm(
    const void* __restrict__ Aptr, const ush* __restrict__ BT,
    ush* __restrict__ C, int M, int K, int NN,
    const float* __restrict__ rowscale, const float* __restrict__ bias,
    float* __restrict__ stats)
{
    __shared__ __align__(16) ush As[128][40];
    __shared__ __align__(16) ush Bs[128][40];
    const int bn0 = blockIdx.x * 128;
    const int bm0 = blockIdx.y * 128;
    const int tid = threadIdx.x;
    const int lane = tid & 63;
    const int wv = tid >> 6;
    const int wm = (wv >> 1) * 64;
    const int wn = (wv & 1) * 64;
    const int lm = lane & 15;
    const int lg = lane >> 4;

    f32x4v zero = {0.f, 0.f, 0.f, 0.f};
    f32x4v acc[4][4];
    #pragma unroll
    for (int mi = 0; mi < 4; mi++)
        #pragma unroll
        for (int ni = 0; ni < 4; ni++) acc[mi][ni] = zero;

    for (int k0 = 0; k0 < K; k0 += 32) {
        #pragma unroll
        for (int i = 0; i < 2; i++) {
            int seg = tid + i * 256;
            int n = seg >> 2, kp = seg & 3;
            su16x8 v = *(const su16x8*)&BT[(size_t)(bn0 + n) * K + k0 + kp * 8];
            *(su16x8*)&Bs[n][kp * 8] = v;
        }
        if constexpr (A_F32) {
            const float* Af = (const float*)Aptr;
            #pragma unroll
            for (int i = 0; i < 4; i++) {
                int seg = tid + i * 256;
                int m = seg >> 3, kp = seg & 7;
                int gm = bm0 + m; if (gm >= M) gm = M - 1;
                float4 v = *(const float4*)&Af[(size_t)gm * K + k0 + kp * 4];
                su16x4 o = { f2bf(v.x), f2bf(v.y), f2bf(v.z), f2bf(v.w) };
                *(su16x4*)&As[m][kp * 4] = o;
            }
        } else {
            const ush* Ab = (const ush*)Aptr;
            #pragma unroll
            for (int i = 0; i < 2; i++) {
                int seg = tid + i * 256;
                int m = seg >> 2, kp = seg & 3;
                int gm = bm0 + m; if (gm >= M) gm = M - 1;
                su16x8 v = *(const su16x8*)&Ab[(size_t)gm * K + k0 + kp * 8];
                *(su16x8*)&As[m][kp * 8] = v;
            }
        }
        __syncthreads();
        su16x8 af[4], bfr[4];
        #pragma unroll
        for (int i = 0; i < 4; i++)
            af[i] = *(const su16x8*)&As[wm + i * 16 + lm][lg * 8];
        #pragma unroll
        for (int i = 0; i < 4; i++)
            bfr[i] = *(const su16x8*)&Bs[wn + i * 16 + lm][lg * 8];
        #pragma unroll
        for (int mi = 0; mi < 4; mi++)
            #pragma unroll
            for (int ni = 0; ni < 4; ni++)
                acc[mi][ni] = MFMA_BF16(af[mi], bfr[ni], acc[mi][ni]);
        __syncthreads();
    }

    float s4[4] = {0.f, 0.f, 0.f, 0.f}, q4[4] = {0.f, 0.f, 0.f, 0.f};
    #pragma unroll
    for (int mi = 0; mi < 4; mi++) {
        #pragma unroll
        for (int j = 0; j < 4; j++) {
            int gm = bm0 + wm + mi * 16 + lg * 4 + j;
            bool valid = gm < M;
            float rs = (rowscale && valid) ? rowscale[gm] : 1.f;
            #pragma unroll
            for (int ni = 0; ni < 4; ni++) {
                int gn = bn0 + wn + ni * 16 + lm;
                float v = acc[mi][ni][j] * rs;
                if (bias) v += bias[gn];
                if (valid) {
                    C[(size_t)gm * NN + gn] = f2bf(v);
                    if constexpr (DO_STATS) { s4[ni] += v; q4[ni] += v * v; }
                }
            }
        }
    }
    if constexpr (DO_STATS) {
        #pragma unroll
        for (int ni = 0; ni < 4; ni++) {
            s4[ni] += __shfl_xor(s4[ni], 16); s4[ni] += __shfl_xor(s4[ni], 32);
            q4[ni] += __shfl_xor(q4[ni], 16); q4[ni] += __shfl_xor(q4[ni], 32);
        }
        if (lg == 0) {
            #pragma unroll
            for (int ni = 0; ni < 4; ni++) {
                int gn = bn0 + wn + ni * 16 + lm;
                atomicAdd(&stats[gn], s4[ni]);
                atomicAdd(&stats[HID + gn], q4[ni]);
            }
        }
    }
}

// ---------------- layer-0 aggregation (D=128, plain sum; nsrc pre-applied) ----------------
__global__ __launch_bounds__(256) void agg128(const ush* __restrict__ hs,
                                              const int* __restrict__ roff,
                                              const int* __restrict__ csr,
                                              ush* __restrict__ out)
{
    int node = (blockIdx.x * 256 + threadIdx.x) >> 6;
    int lane = threadIdx.x & 63;
    if (node >= N_NODES) return;
    int q = lane >> 4;              // 4 edges in flight per wave
    int c0 = (lane & 15) * 8;       // 8 bf16 channels per lane (16B)
    int beg = roff[node], end = roff[node + 1];
    float acc[8] = {};
    for (int e = beg + q; e < end; e += 4) {
        int s = csr[e];
        su16x8 v = *(const su16x8*)&hs[(size_t)s * 128 + c0];
        #pragma unroll
        for (int j = 0; j < 8; j++) acc[j] += bf2f(v[j]);
    }
    #pragma unroll
    for (int j = 0; j < 8; j++) {
        acc[j] += __shfl_xor(acc[j], 16);
        acc[j] += __shfl_xor(acc[j], 32);
    }
    if (lane < 16) {
        su16x8 o;
        #pragma unroll
        for (int j = 0; j < 8; j++) o[j] = f2bf(acc[j]);
        *(su16x8*)&out[(size_t)node * 128 + c0] = o;
    }
}

// ---------------- layers 1,2 aggregation (D=256) with fused BN+ReLU+nsrc ----------------
__global__ __launch_bounds__(256) void agg256_bn(const ush* __restrict__ pre,
                                                 const float* __restrict__ bnab,
                                                 const float* __restrict__ nsrc,
                                                 const int* __restrict__ roff,
                                                 const int* __restrict__ csr,
                                                 ush* __restrict__ out)
{
    int node = (blockIdx.x * 256 + threadIdx.x) >> 6;
    int lane = threadIdx.x & 63;
    if (node >= N_NODES) return;
    int half = lane >> 5;           // 2 edges in flight per wave
    int c0 = (lane & 31) * 8;       // 8 bf16 channels per lane (16B)
    float a[8], b[8];
    #pragma unroll
    for (int j = 0; j < 8; j++) { a[j] = bnab[c0 + j]; b[j] = bnab[HID + c0 + j]; }
    int beg = roff[node], end = roff[node + 1];
    float acc[8] = {};
    for (int e = beg + half; e < end; e += 2) {
        int s = csr[e];
        float ns = nsrc[s];
        su16x8 v = *(const su16x8*)&pre[(size_t)s * 256 + c0];
        #pragma unroll
        for (int j = 0; j < 8; j++) {
            float x = fmaxf(fmaf(bf2f(v[j]), a[j], b[j]), 0.f);
            acc[j] = fmaf(x, ns, acc[j]);
        }
    }
    #pragma unroll
    for (int j = 0; j < 8; j++) acc[j] += __shfl_xor(acc[j], 32);
    if (lane < 32) {
        su16x8 o;
        #pragma unroll
        for (int j = 0; j < 8; j++) o[j] = f2bf(acc[j]);
        *(su16x8*)&out[(size_t)node * 256 + c0] = o;
    }
}

// ---------------- BN prep: stats -> per-channel scale/shift ----------------
__global__ void bnprep_kernel(const float* __restrict__ stats,
                              const float* __restrict__ gamma, const float* __restrict__ beta,
                              float* __restrict__ ab) {
    int c = threadIdx.x;   // 256
    const float inv_n = 1.f / (float)N_NODES;
    float mu = stats[c] * inv_n;
    float var = fmaf(-mu, mu, stats[HID + c] * inv_n);
    float a = gamma[c] * rsqrtf(var + BN_EPS);
    ab[c] = a;
    ab[HID + c] = fmaf(-mu, a, beta[c]);
}

// ---------------- graph start offsets ----------------
__global__ void gstart_kernel(const int* __restrict__ gids, int* __restrict__ gstart) {
    int n = blockIdx.x * 256 + threadIdx.x;
    if (n >= N_NODES) return;
    int g = gids[n];
    int gp = (n == 0) ? -1 : gids[n - 1];
    for (int gg = gp + 1; gg <= g; gg++) gstart[gg] = n;
    if (n == N_NODES - 1) {
        for (int gg = g + 1; gg <= N_GRAPHS; gg++) gstart[gg] = N_NODES;
    }
}

// ---------------- per-graph max with fused BN+ReLU (values >= 0; hg pre-zeroed) ----------------
__global__ void segmax_bn(const ush* __restrict__ pre, const float* __restrict__ bnab,
                          const int* __restrict__ gstart, float* __restrict__ hg) {
    int g = blockIdx.x;
    int chunk = blockIdx.y;                 // 8 chunks per graph
    int c = threadIdx.x;
    float a = bnab[c], b = bnab[HID + c];
    int beg = gstart[g], end = gstart[g + 1];
    int len = end - beg;
    int per = (len + 7) >> 3;
    int s = beg + chunk * per;
    int e = s + per; if (e > end) e = end;
    float m = 0.f;
    for (int n = s; n < e; n++)
        m = fmaxf(m, fmaf(bf2f(pre[(size_t)n * HID + c]), a, b));
    m = fmaxf(m, 0.f);
    atomicMax((int*)&hg[g * HID + c], __float_as_int(m));
}

// ---------------- final fc ----------------
__global__ void fc_kernel(const float* __restrict__ hg, const float* __restrict__ w,
                          const float* __restrict__ b, float* __restrict__ out) {
    int idx = blockIdx.x * 256 + threadIdx.x;
    if (idx >= N_GRAPHS * OUT_DIM) return;
    int g = idx / OUT_DIM, j = idx % OUT_DIM;
    float s = b[j];
    for (int c = 0; c < HID; c++) s += hg[g * HID + c] * w[c * OUT_DIM + j];
    out[idx] = s;
}

extern "C" void kernel_launch(void* const* d_in, const int* in_sizes, int n_in,
                              void* d_out, int out_size, void* d_ws, size_t ws_size,
                              hipStream_t stream) {
    const float* h      = (const float*)d_in[0];
    const int*   src    = (const int*)d_in[1];
    const int*   dst    = (const int*)d_in[2];
    const int*   gids   = (const int*)d_in[3];
    const float* w_init = (const float*)d_in[4];
    const float* lw[3]    = { (const float*)d_in[5],  (const float*)d_in[9],  (const float*)d_in[13] };
    const float* lb[3]    = { (const float*)d_in[6],  (const float*)d_in[10], (const float*)d_in[14] };
    const float* gamma[3] = { (const float*)d_in[7],  (const float*)d_in[11], (const float*)d_in[15] };
    const float* beta[3]  = { (const float*)d_in[8],  (const float*)d_in[12], (const float*)d_in[16] };
    const float* fc_w = (const float*)d_in[17];
    const float* fc_b = (const float*)d_in[18];
    float* out = (float*)d_out;

    // ---- workspace layout ----
    char* ws = (char*)d_ws;
    size_t off = 0;
    auto alloc = [&](size_t bytes) { size_t o = off; off += (bytes + 255) & ~(size_t)255; return o; };
    size_t o_h0s   = alloc((size_t)N_NODES * NCLS * 2);      // bf16 [N,128]
    size_t o_aggb  = alloc((size_t)N_NODES * HID * 2);       // bf16 [N,256]
    size_t o_P0    = alloc((size_t)N_NODES * HID * 2);       // pre-BN ping
    size_t o_P1    = alloc((size_t)N_NODES * HID * 2);       // pre-BN pong
    size_t o_wB0   = alloc((size_t)NCLS * FIN * 2);
    size_t o_lwT0  = alloc((size_t)HID * NCLS * 2);
    size_t o_lwT1  = alloc((size_t)HID * HID * 2);
    size_t o_lwT2  = alloc((size_t)HID * HID * 2);
    size_t o_nsrc  = alloc((size_t)N_NODES * 4);
    size_t o_ndst  = alloc((size_t)N_NODES * 4);
    size_t o_odeg  = alloc((size_t)N_NODES * 4);
    size_t o_ideg  = alloc((size_t)N_NODES * 4);
    size_t o_roff  = alloc((size_t)(N_NODES + 1) * 4);
    size_t o_cur   = alloc((size_t)N_NODES * 4);
    size_t o_csr   = alloc((size_t)N_EDGES * 4);
    size_t o_bsum  = alloc((size_t)SCAN_BLOCKS * 4);
    size_t o_boff  = alloc((size_t)SCAN_BLOCKS * 4);
    size_t o_stats = alloc((size_t)3 * 2 * HID * 4);         // 3 layers x (sum,sumsq)
    size_t o_bnab  = alloc((size_t)3 * 2 * HID * 4);         // 3 layers x (a,b)
    size_t o_gst   = alloc((size_t)(N_GRAPHS + 1) * 4);
    size_t o_hg    = alloc((size_t)N_GRAPHS * HID * 4);
    if (off > ws_size) return;

    ush*   h0s  = (ush*)(ws + o_h0s);
    ush*   aggb = (ush*)(ws + o_aggb);
    ush*   P[2] = { (ush*)(ws + o_P0), (ush*)(ws + o_P1) };
    ush*   wB0  = (ush*)(ws + o_wB0);
    ush*   lwT[3] = { (ush*)(ws + o_lwT0), (ush*)(ws + o_lwT1), (ush*)(ws + o_lwT2) };
    float* nsrc = (float*)(ws + o_nsrc);
    float* ndst = (float*)(ws + o_ndst);
    int*   odeg = (int*)(ws + o_odeg);
    int*   ideg = (int*)(ws + o_ideg);
    int*   roff = (int*)(ws + o_roff);
    int*   cur  = (int*)(ws + o_cur);
    int*   csr  = (int*)(ws + o_csr);
    int*   bsum = (int*)(ws + o_bsum);
    int*   boff = (int*)(ws + o_boff);
    float* stats= (float*)(ws + o_stats);
    float* bnab = (float*)(ws + o_bnab);
    int*   gst  = (int*)(ws + o_gst);
    float* hg   = (float*)(ws + o_hg);

    const int eb = (N_EDGES + 255) / 256;
    const int nb = (N_NODES + 255) / 256;

    // zero accumulators (inside the captured graph: deterministic per launch)
    hipMemsetAsync(odeg, 0, (size_t)N_NODES * 4, stream);
    hipMemsetAsync(ideg, 0, (size_t)N_NODES * 4, stream);
    hipMemsetAsync(stats, 0, 3 * 2 * HID * 4, stream);
    hipMemsetAsync(hg, 0, (size_t)N_GRAPHS * HID * 4, stream);

    deg_kernel<<<eb, 256, 0, stream>>>(src, dst, odeg, ideg);
    norm_kernel<<<nb, 256, 0, stream>>>(odeg, ideg, nsrc, ndst);

    // CSR by dst (parallel scan)
    scan1_kernel<<<SCAN_BLOCKS, 256, 0, stream>>>(ideg, bsum);
    scan2_kernel<<<1, 512, 0, stream>>>(bsum, boff);
    scan3_kernel<<<SCAN_BLOCKS, 256, 0, stream>>>(ideg, boff, roff, cur);
    fill_kernel<<<eb, 256, 0, stream>>>(src, dst, cur, csr);

    gstart_kernel<<<nb, 256, 0, stream>>>(gids, gst);

    // weight prep
    cvt_w0_kernel<<<(NCLS * FIN + 255) / 256, 256, 0, stream>>>(w_init, wB0);
    cvt_lwT_kernel<<<(NCLS * HID + 255) / 256, 256, 0, stream>>>(lw[0], lwT[0], NCLS);
    cvt_lwT_kernel<<<(HID * HID + 255) / 256, 256, 0, stream>>>(lw[1], lwT[1], HID);
    cvt_lwT_kernel<<<(HID * HID + 255) / 256, 256, 0, stream>>>(lw[2], lwT[2], HID);

    const int mblocks = (N_NODES + 127) / 128;
    const int aggblocks = (N_NODES * 64 + 255) / 256;

    // h0s = (h @ w_init^T) * nsrc   [N,128] bf16
    {
        dim3 grid(NCLS / 128, mblocks);
        mfma_gemm<true, false><<<grid, 256, 0, stream>>>(h, wB0, h0s, N_NODES, FIN, NCLS,
                                                         nsrc, nullptr, nullptr);
    }

    // ---- layer 0 ----
    agg128<<<aggblocks, 256, 0, stream>>>(h0s, roff, csr, aggb);
    {
        dim3 grid(HID / 128, mblocks);
        mfma_gemm<false, true><<<grid, 256, 0, stream>>>(aggb, lwT[0], P[0], N_NODES, NCLS, HID,
                                                         ndst, lb[0], stats);
    }
    bnprep_kernel<<<1, 256, 0, stream>>>(stats, gamma[0], beta[0], bnab);

    // ---- layers 1,2 ----
    for (int l = 1; l < 3; l++) {
        ush* pin  = P[(l + 1) & 1];
        ush* pout = P[l & 1];
        agg256_bn<<<aggblocks, 256, 0, stream>>>(pin, bnab + (l - 1) * 2 * HID, nsrc,
                                                 roff, csr, aggb);
        dim3 grid(HID / 128, mblocks);
        mfma_gemm<false, true><<<grid, 256, 0, stream>>>(aggb, lwT[l], pout, N_NODES, HID, HID,
                                                         ndst, lb[l], stats + l * 2 * HID);
        bnprep_kernel<<<1, 256, 0, stream>>>(stats + l * 2 * HID, gamma[l], beta[l],
                                             bnab + l * 2 * HID);
    }

    // ---- readout: per-graph max of BN(P2)+ReLU, then fc ----
    {
        dim3 grid(N_GRAPHS, 8);
        segmax_bn<<<grid, 256, 0, stream>>>(P[0], bnab + 2 * 2 * HID, gst, hg);
    }
    fc_kernel<<<(N_GRAPHS * OUT_DIM + 255) / 256, 256, 0, stream>>>(hg, fc_w, fc_b, out);
}

// Round 4
// 1159.847 us; speedup vs baseline: 2.6240x; 1.2608x over previous
//
#include <hip/hip_runtime.h>
#include <hip/hip_bf16.h>

#define N_NODES 100000
#define N_EDGES 3200000
#define N_GRAPHS 128
#define FIN 512
#define NCLS 128
#define HID 256
#define OUT_DIM 10
#define BN_EPS 1e-5f

#define NBUCK 391                      // ceil(N_NODES/256): bucket = dst >> 8
#define EPB   ((N_EDGES + NBUCK - 1) / NBUCK)   // edges per partition block

typedef unsigned short ush;
typedef ush su16x8 __attribute__((ext_vector_type(8)));
typedef ush su16x4 __attribute__((ext_vector_type(4)));
typedef __bf16 bf16x8v __attribute__((ext_vector_type(8)));
typedef float f32x4v __attribute__((ext_vector_type(4)));

__device__ __forceinline__ float bf2f(ush u) {
    union { unsigned int i; float f; } v; v.i = ((unsigned int)u) << 16; return v.f;
}
__device__ __forceinline__ ush f2bf(float f) {
    union { float f; unsigned int i; } v; v.f = f;
    unsigned int r = v.i + 0x7FFFu + ((v.i >> 16) & 1u);
    return (ush)(r >> 16);
}

// MFMA shim: works whether the gfx950 builtin takes 16-bit-int vectors or __bf16 vectors.
template <typename T>
__device__ __forceinline__ auto mfma_sel(T a, T b, f32x4v c, int)
    -> decltype(__builtin_amdgcn_mfma_f32_16x16x32_bf16(a, b, c, 0, 0, 0)) {
    return __builtin_amdgcn_mfma_f32_16x16x32_bf16(a, b, c, 0, 0, 0);
}
template <typename T>
__device__ __forceinline__ f32x4v mfma_sel(T a, T b, f32x4v c, long) {
    return __builtin_amdgcn_mfma_f32_16x16x32_bf16(
        __builtin_bit_cast(bf16x8v, a), __builtin_bit_cast(bf16x8v, b), c, 0, 0, 0);
}
__device__ __forceinline__ f32x4v MFMA_BF16(su16x8 a, su16x8 b, f32x4v c) {
    return mfma_sel(a, b, c, 0);
}

// ---------------- out-degree + nsrc ----------------
__global__ void odeg_kernel(const int* __restrict__ src, int* __restrict__ odeg) {
    int e = blockIdx.x * 256 + threadIdx.x;
    if (e < N_EDGES) atomicAdd(&odeg[src[e]], 1);
}
__global__ void nsrc_kernel(const int* __restrict__ odeg, float* __restrict__ nsrc) {
    int n = blockIdx.x * 256 + threadIdx.x;
    if (n < N_NODES) {
        int od = odeg[n];
        nsrc[n] = od > 0 ? rsqrtf((float)od) : 0.f;
    }
}

// ---------------- CSR partition: pass A — per-block bucket histogram ----------------
__global__ __launch_bounds__(256) void histA_kernel(const int* __restrict__ dst,
                                                    int* __restrict__ hist) {
    __shared__ int hc[NBUCK];
    int tid = threadIdx.x, blk = blockIdx.x;
    for (int i = tid; i < NBUCK; i += 256) hc[i] = 0;
    __syncthreads();
    int e0 = blk * EPB, e1 = e0 + EPB; if (e1 > N_EDGES) e1 = N_EDGES;
    for (int e = e0 + tid; e < e1; e += 256) atomicAdd(&hc[dst[e] >> 8], 1);
    __syncthreads();
    for (int i = tid; i < NBUCK; i += 256) hist[(size_t)blk * NBUCK + i] = hc[i];
}

// ---------------- pass B1 — bucket totals ----------------
__global__ __launch_bounds__(512) void bcnt_kernel(const int* __restrict__ hist,
                                                   int* __restrict__ bcnt) {
    __shared__ int ws[8];
    int b = blockIdx.x, tid = threadIdx.x;
    int lane = tid & 63, wid = tid >> 6;
    int v = (tid < NBUCK) ? hist[(size_t)tid * NBUCK + b] : 0;
    #pragma unroll
    for (int off = 32; off > 0; off >>= 1) v += __shfl_down(v, off, 64);
    if (lane == 0) ws[wid] = v;
    __syncthreads();
    if (tid == 0) {
        int s = 0;
        #pragma unroll
        for (int w = 0; w < 8; w++) s += ws[w];
        bcnt[b] = s;
    }
}

// ---------------- pass Bscan — exclusive scan of bucket totals ----------------
__global__ __launch_bounds__(512) void bscan_kernel(const int* __restrict__ bcnt,
                                                    int* __restrict__ bbase) {
    __shared__ int a[512];
    int tid = threadIdx.x;
    int v = (tid < NBUCK) ? bcnt[tid] : 0;
    a[tid] = v;
    __syncthreads();
    for (int s = 1; s < 512; s <<= 1) {
        int y = (tid >= s) ? a[tid - s] : 0;
        __syncthreads();
        a[tid] += y;
        __syncthreads();
    }
    if (tid < NBUCK) bbase[tid] = a[tid] - v;
    if (tid == 0) bbase[NBUCK] = N_EDGES;
}

// ---------------- pass B2 — per-(block,bucket) offsets ----------------
__global__ __launch_bounds__(512) void boff_kernel(const int* __restrict__ hist,
                                                   const int* __restrict__ bbase,
                                                   int* __restrict__ off) {
    __shared__ int a[512];
    int b = blockIdx.x, tid = threadIdx.x;
    int v = (tid < NBUCK) ? hist[(size_t)tid * NBUCK + b] : 0;
    a[tid] = v;
    __syncthreads();
    for (int s = 1; s < 512; s <<= 1) {
        int y = (tid >= s) ? a[tid - s] : 0;
        __syncthreads();
        a[tid] += y;
        __syncthreads();
    }
    if (tid < NBUCK) off[(size_t)tid * NBUCK + b] = bbase[b] + a[tid] - v;
}

// ---------------- pass C — stage edges into bucket-contiguous runs ----------------
__global__ __launch_bounds__(256) void stage_kernel(const int* __restrict__ src,
                                                    const int* __restrict__ dst,
                                                    const int* __restrict__ off,
                                                    unsigned int* __restrict__ staged) {
    __shared__ int cur[NBUCK];
    int tid = threadIdx.x, blk = blockIdx.x;
    for (int i = tid; i < NBUCK; i += 256) cur[i] = off[(size_t)blk * NBUCK + i];
    __syncthreads();
    int e0 = blk * EPB, e1 = e0 + EPB; if (e1 > N_EDGES) e1 = N_EDGES;
    for (int e = e0 + tid; e < e1; e += 256) {
        int d = dst[e], s = src[e];
        int pos = atomicAdd(&cur[d >> 8], 1);
        staged[pos] = ((unsigned int)(d & 255) << 24) | (unsigned int)s;
    }
}

// ---------------- pass D — exact CSR within bucket + roff + ndst ----------------
__global__ __launch_bounds__(256) void csr_kernel(const unsigned int* __restrict__ staged,
                                                  const int* __restrict__ bbase,
                                                  int* __restrict__ roff,
                                                  float* __restrict__ ndst,
                                                  int* __restrict__ csr) {
    __shared__ int cnt[256], pfx[256], cur[256];
    int b = blockIdx.x, tid = threadIdx.x;
    int beg = bbase[b], end = bbase[b + 1];
    int nodeBase = b * 256;
    int nNodes = N_NODES - nodeBase; if (nNodes > 256) nNodes = 256;
    cnt[tid] = 0;
    __syncthreads();
    for (int e = beg + tid; e < end; e += 256) atomicAdd(&cnt[staged[e] >> 24], 1);
    __syncthreads();
    int v = cnt[tid];
    pfx[tid] = v;
    __syncthreads();
    for (int s = 1; s < 256; s <<= 1) {
        int y = (tid >= s) ? pfx[tid - s] : 0;
        __syncthreads();
        pfx[tid] += y;
        __syncthreads();
    }
    int excl = pfx[tid] - v;
    pfx[tid] = excl;           // exclusive prefix, kept in LDS for phase 2
    cur[tid] = 0;
    if (tid < nNodes) {
        int node = nodeBase + tid;
        roff[node] = beg + excl;
        ndst[node] = v > 0 ? rsqrtf((float)v) : 0.f;
    }
    if (b == NBUCK - 1 && tid == 0) roff[N_NODES] = N_EDGES;
    __syncthreads();
    for (int e = beg + tid; e < end; e += 256) {
        unsigned int w = staged[e];
        int dl = w >> 24;
        int pos = beg + pfx[dl] + atomicAdd(&cur[dl], 1);
        csr[pos] = (int)(w & 0xFFFFFFu);
    }
}

// ---------------- weight prep ----------------
__global__ void cvt_w0_kernel(const float* __restrict__ w, ush* __restrict__ o) {
    int i = blockIdx.x * 256 + threadIdx.x;
    if (i < NCLS * FIN) o[i] = f2bf(w[i]);
}
// lw [K][HID] -> o [HID][K] bf16 (B^T)
__global__ void cvt_lwT_kernel(const float* __restrict__ lw, ush* __restrict__ o, int K) {
    int i = blockIdx.x * 256 + threadIdx.x;
    if (i < K * HID) {
        int n = i / K, k = i % K;
        o[i] = f2bf(lw[(size_t)k * HID + n]);
    }
}

// ---------------- MFMA GEMM: C[M,NN](bf16) = A[M,K] @ BT[NN,K]^T ----------------
template <bool A_F32, bool DO_STATS>
__global__ __launch_bounds__(256) void mfma_gemm(
    const void* __restrict__ Aptr, const ush* __restrict__ BT,
    ush* __restrict__ C, int M, int K, int NN,
    const float* __restrict__ rowscale, const float* __restrict__ bias,
    float* __restrict__ stats)
{
    __shared__ __align__(16) ush As[128][40];
    __shared__ __align__(16) ush Bs[128][40];
    const int bn0 = blockIdx.x * 128;
    const int bm0 = blockIdx.y * 128;
    const int tid = threadIdx.x;
    const int lane = tid & 63;
    const int wv = tid >> 6;
    const int wm = (wv >> 1) * 64;
    const int wn = (wv & 1) * 64;
    const int lm = lane & 15;
    const int lg = lane >> 4;

    f32x4v zero = {0.f, 0.f, 0.f, 0.f};
    f32x4v acc[4][4];
    #pragma unroll
    for (int mi = 0; mi < 4; mi++)
        #pragma unroll
        for (int ni = 0; ni < 4; ni++) acc[mi][ni] = zero;

    for (int k0 = 0; k0 < K; k0 += 32) {
        #pragma unroll
        for (int i = 0; i < 2; i++) {
            int seg = tid + i * 256;
            int n = seg >> 2, kp = seg & 3;
            su16x8 v = *(const su16x8*)&BT[(size_t)(bn0 + n) * K + k0 + kp * 8];
            *(su16x8*)&Bs[n][kp * 8] = v;
        }
        if constexpr (A_F32) {
            const float* Af = (const float*)Aptr;
            #pragma unroll
            for (int i = 0; i < 4; i++) {
                int seg = tid + i * 256;
                int m = seg >> 3, kp = seg & 7;
                int gm = bm0 + m; if (gm >= M) gm = M - 1;
                float4 v = *(const float4*)&Af[(size_t)gm * K + k0 + kp * 4];
                su16x4 o = { f2bf(v.x), f2bf(v.y), f2bf(v.z), f2bf(v.w) };
                *(su16x4*)&As[m][kp * 4] = o;
            }
        } else {
            const ush* Ab = (const ush*)Aptr;
            #pragma unroll
            for (int i = 0; i < 2; i++) {
                int seg = tid + i * 256;
                int m = seg >> 2, kp = seg & 3;
                int gm = bm0 + m; if (gm >= M) gm = M - 1;
                su16x8 v = *(const su16x8*)&Ab[(size_t)gm * K + k0 + kp * 8];
                *(su16x8*)&As[m][kp * 8] = v;
            }
        }
        __syncthreads();
        su16x8 af[4], bfr[4];
        #pragma unroll
        for (int i = 0; i < 4; i++)
            af[i] = *(const su16x8*)&As[wm + i * 16 + lm][lg * 8];
        #pragma unroll
        for (int i = 0; i < 4; i++)
            bfr[i] = *(const su16x8*)&Bs[wn + i * 16 + lm][lg * 8];
        #pragma unroll
        for (int mi = 0; mi < 4; mi++)
            #pragma unroll
            for (int ni = 0; ni < 4; ni++)
                acc[mi][ni] = MFMA_BF16(af[mi], bfr[ni], acc[mi][ni]);
        __syncthreads();
    }

    float s4[4] = {0.f, 0.f, 0.f, 0.f}, q4[4] = {0.f, 0.f, 0.f, 0.f};
    #pragma unroll
    for (int mi = 0; mi < 4; mi++) {
        #pragma unroll
        for (int j = 0; j < 4; j++) {
            int gm = bm0 + wm + mi * 16 + lg * 4 + j;
            bool valid = gm < M;
            float rs = (rowscale && valid) ? rowscale[gm] : 1.f;
            #pragma unroll
            for (int ni = 0; ni < 4; ni++) {
                int gn = bn0 + wn + ni * 16 + lm;
                float v = acc[mi][ni][j] * rs;
                if (bias) v += bias[gn];
                if (valid) {
                    C[(size_t)gm * NN + gn] = f2bf(v);
                    if constexpr (DO_STATS) { s4[ni] += v; q4[ni] += v * v; }
                }
            }
        }
    }
    if constexpr (DO_STATS) {
        #pragma unroll
        for (int ni = 0; ni < 4; ni++) {
            s4[ni] += __shfl_xor(s4[ni], 16); s4[ni] += __shfl_xor(s4[ni], 32);
            q4[ni] += __shfl_xor(q4[ni], 16); q4[ni] += __shfl_xor(q4[ni], 32);
        }
        if (lg == 0) {
            #pragma unroll
            for (int ni = 0; ni < 4; ni++) {
                int gn = bn0 + wn + ni * 16 + lm;
                atomicAdd(&stats[gn], s4[ni]);
                atomicAdd(&stats[HID + gn], q4[ni]);
            }
        }
    }
}

// ---------------- layer-0 aggregation (D=128, plain sum) ----------------
__global__ __launch_bounds__(256) void agg128(const ush* __restrict__ hs,
                                              const int* __restrict__ roff,
                                              const int* __restrict__ csr,
                                              ush* __restrict__ out)
{
    int node = (blockIdx.x * 256 + threadIdx.x) >> 6;
    int lane = threadIdx.x & 63;
    if (node >= N_NODES) return;
    int q = lane >> 4;              // 4 edges in flight per wave
    int c0 = (lane & 15) * 8;
    int beg = roff[node], end = roff[node + 1];
    float acc[8] = {};
    for (int e = beg + q; e < end; e += 4) {
        int s = csr[e];
        su16x8 v = *(const su16x8*)&hs[(size_t)s * 128 + c0];
        #pragma unroll
        for (int j = 0; j < 8; j++) acc[j] += bf2f(v[j]);
    }
    #pragma unroll
    for (int j = 0; j < 8; j++) {
        acc[j] += __shfl_xor(acc[j], 16);
        acc[j] += __shfl_xor(acc[j], 32);
    }
    if (lane < 16) {
        su16x8 o;
        #pragma unroll
        for (int j = 0; j < 8; j++) o[j] = f2bf(acc[j]);
        *(su16x8*)&out[(size_t)node * 128 + c0] = o;
    }
}

// ---------------- layers 1,2 aggregation (D=256) with fused BN+ReLU+nsrc ----------------
__global__ __launch_bounds__(256) void agg256_bn(const ush* __restrict__ pre,
                                                 const float* __restrict__ bnab,
                                                 const float* __restrict__ nsrc,
                                                 const int* __restrict__ roff,
                                                 const int* __restrict__ csr,
                                                 ush* __restrict__ out)
{
    int node = (blockIdx.x * 256 + threadIdx.x) >> 6;
    int lane = threadIdx.x & 63;
    if (node >= N_NODES) return;
    int half = lane >> 5;           // 2 edges in flight per wave
    int c0 = (lane & 31) * 8;
    float a[8], b[8];
    #pragma unroll
    for (int j = 0; j < 8; j++) { a[j] = bnab[c0 + j]; b[j] = bnab[HID + c0 + j]; }
    int beg = roff[node], end = roff[node + 1];
    float acc[8] = {};
    for (int e = beg + half; e < end; e += 2) {
        int s = csr[e];
        float ns = nsrc[s];
        su16x8 v = *(const su16x8*)&pre[(size_t)s * 256 + c0];
        #pragma unroll
        for (int j = 0; j < 8; j++) {
            float x = fmaxf(fmaf(bf2f(v[j]), a[j], b[j]), 0.f);
            acc[j] = fmaf(x, ns, acc[j]);
        }
    }
    #pragma unroll
    for (int j = 0; j < 8; j++) acc[j] += __shfl_xor(acc[j], 32);
    if (lane < 32) {
        su16x8 o;
        #pragma unroll
        for (int j = 0; j < 8; j++) o[j] = f2bf(acc[j]);
        *(su16x8*)&out[(size_t)node * 256 + c0] = o;
    }
}

// ---------------- BN prep: stats -> per-channel scale/shift ----------------
__global__ void bnprep_kernel(const float* __restrict__ stats,
                              const float* __restrict__ gamma, const float* __restrict__ beta,
                              float* __restrict__ ab) {
    int c = threadIdx.x;
    const float inv_n = 1.f / (float)N_NODES;
    float mu = stats[c] * inv_n;
    float var = fmaf(-mu, mu, stats[HID + c] * inv_n);
    float a = gamma[c] * rsqrtf(var + BN_EPS);
    ab[c] = a;
    ab[HID + c] = fmaf(-mu, a, beta[c]);
}

// ---------------- graph start offsets ----------------
__global__ void gstart_kernel(const int* __restrict__ gids, int* __restrict__ gstart) {
    int n = blockIdx.x * 256 + threadIdx.x;
    if (n >= N_NODES) return;
    int g = gids[n];
    int gp = (n == 0) ? -1 : gids[n - 1];
    for (int gg = gp + 1; gg <= g; gg++) gstart[gg] = n;
    if (n == N_NODES - 1) {
        for (int gg = g + 1; gg <= N_GRAPHS; gg++) gstart[gg] = N_NODES;
    }
}

// ---------------- per-graph max with fused BN+ReLU (values >= 0; hg pre-zeroed) ----------------
__global__ void segmax_bn(const ush* __restrict__ pre, const float* __restrict__ bnab,
                          const int* __restrict__ gstart, float* __restrict__ hg) {
    int g = blockIdx.x;
    int chunk = blockIdx.y;
    int c = threadIdx.x;
    float a = bnab[c], b = bnab[HID + c];
    int beg = gstart[g], end = gstart[g + 1];
    int len = end - beg;
    int per = (len + 7) >> 3;
    int s = beg + chunk * per;
    int e = s + per; if (e > end) e = end;
    float m = 0.f;
    for (int n = s; n < e; n++)
        m = fmaxf(m, fmaf(bf2f(pre[(size_t)n * HID + c]), a, b));
    m = fmaxf(m, 0.f);
    atomicMax((int*)&hg[g * HID + c], __float_as_int(m));
}

// ---------------- final fc ----------------
__global__ void fc_kernel(const float* __restrict__ hg, const float* __restrict__ w,
                          const float* __restrict__ b, float* __restrict__ out) {
    int idx = blockIdx.x * 256 + threadIdx.x;
    if (idx >= N_GRAPHS * OUT_DIM) return;
    int g = idx / OUT_DIM, j = idx % OUT_DIM;
    float s = b[j];
    for (int c = 0; c < HID; c++) s += hg[g * HID + c] * w[c * OUT_DIM + j];
    out[idx] = s;
}

extern "C" void kernel_launch(void* const* d_in, const int* in_sizes, int n_in,
                              void* d_out, int out_size, void* d_ws, size_t ws_size,
                              hipStream_t stream) {
    const float* h      = (const float*)d_in[0];
    const int*   src    = (const int*)d_in[1];
    const int*   dst    = (const int*)d_in[2];
    const int*   gids   = (const int*)d_in[3];
    const float* w_init = (const float*)d_in[4];
    const float* lw[3]    = { (const float*)d_in[5],  (const float*)d_in[9],  (const float*)d_in[13] };
    const float* lb[3]    = { (const float*)d_in[6],  (const float*)d_in[10], (const float*)d_in[14] };
    const float* gamma[3] = { (const float*)d_in[7],  (const float*)d_in[11], (const float*)d_in[15] };
    const float* beta[3]  = { (const float*)d_in[8],  (const float*)d_in[12], (const float*)d_in[16] };
    const float* fc_w = (const float*)d_in[17];
    const float* fc_b = (const float*)d_in[18];
    float* out = (float*)d_out;

    // ---- workspace layout ----
    char* ws = (char*)d_ws;
    size_t off_b = 0;
    auto alloc = [&](size_t bytes) { size_t o = off_b; off_b += (bytes + 255) & ~(size_t)255; return o; };
    size_t o_h0s   = alloc((size_t)N_NODES * NCLS * 2);
    size_t o_aggb  = alloc((size_t)N_NODES * HID * 2);
    size_t o_P0    = alloc((size_t)N_NODES * HID * 2);
    size_t o_P1    = alloc((size_t)N_NODES * HID * 2);
    size_t o_wB0   = alloc((size_t)NCLS * FIN * 2);
    size_t o_lwT0  = alloc((size_t)HID * NCLS * 2);
    size_t o_lwT1  = alloc((size_t)HID * HID * 2);
    size_t o_lwT2  = alloc((size_t)HID * HID * 2);
    size_t o_nsrc  = alloc((size_t)N_NODES * 4);
    size_t o_ndst  = alloc((size_t)N_NODES * 4);
    size_t o_odeg  = alloc((size_t)N_NODES * 4);
    size_t o_roff  = alloc((size_t)(N_NODES + 1) * 4);
    size_t o_csr   = alloc((size_t)N_EDGES * 4);
    size_t o_stg   = alloc((size_t)N_EDGES * 4);
    size_t o_hist  = alloc((size_t)NBUCK * NBUCK * 4);
    size_t o_off   = alloc((size_t)NBUCK * NBUCK * 4);
    size_t o_bcnt  = alloc((size_t)(NBUCK + 1) * 4);
    size_t o_bbase = alloc((size_t)(NBUCK + 1) * 4);
    size_t o_stats = alloc((size_t)3 * 2 * HID * 4);
    size_t o_bnab  = alloc((size_t)3 * 2 * HID * 4);
    size_t o_gst   = alloc((size_t)(N_GRAPHS + 1) * 4);
    size_t o_hg    = alloc((size_t)N_GRAPHS * HID * 4);
    if (off_b > ws_size) return;

    ush*   h0s  = (ush*)(ws + o_h0s);
    ush*   aggb = (ush*)(ws + o_aggb);
    ush*   P[2] = { (ush*)(ws + o_P0), (ush*)(ws + o_P1) };
    ush*   wB0  = (ush*)(ws + o_wB0);
    ush*   lwT[3] = { (ush*)(ws + o_lwT0), (ush*)(ws + o_lwT1), (ush*)(ws + o_lwT2) };
    float* nsrc = (float*)(ws + o_nsrc);
    float* ndst = (float*)(ws + o_ndst);
    int*   odeg = (int*)(ws + o_odeg);
    int*   roff = (int*)(ws + o_roff);
    int*   csr  = (int*)(ws + o_csr);
    unsigned int* stg = (unsigned int*)(ws + o_stg);
    int*   hist = (int*)(ws + o_hist);
    int*   boff = (int*)(ws + o_off);
    int*   bcnt = (int*)(ws + o_bcnt);
    int*   bbase= (int*)(ws + o_bbase);
    float* stats= (float*)(ws + o_stats);
    float* bnab = (float*)(ws + o_bnab);
    int*   gst  = (int*)(ws + o_gst);
    float* hg   = (float*)(ws + o_hg);

    const int eb = (N_EDGES + 255) / 256;
    const int nb = (N_NODES + 255) / 256;

    hipMemsetAsync(odeg, 0, (size_t)N_NODES * 4, stream);
    hipMemsetAsync(stats, 0, 3 * 2 * HID * 4, stream);
    hipMemsetAsync(hg, 0, (size_t)N_GRAPHS * HID * 4, stream);

    // out-degree + nsrc
    odeg_kernel<<<eb, 256, 0, stream>>>(src, odeg);
    nsrc_kernel<<<nb, 256, 0, stream>>>(odeg, nsrc);

    // bucketed CSR build (XCD-local scatter)
    histA_kernel<<<NBUCK, 256, 0, stream>>>(dst, hist);
    bcnt_kernel<<<NBUCK, 512, 0, stream>>>(hist, bcnt);
    bscan_kernel<<<1, 512, 0, stream>>>(bcnt, bbase);
    boff_kernel<<<NBUCK, 512, 0, stream>>>(hist, bbase, boff);
    stage_kernel<<<NBUCK, 256, 0, stream>>>(src, dst, boff, stg);
    csr_kernel<<<NBUCK, 256, 0, stream>>>(stg, bbase, roff, ndst, csr);

    gstart_kernel<<<nb, 256, 0, stream>>>(gids, gst);

    // weight prep
    cvt_w0_kernel<<<(NCLS * FIN + 255) / 256, 256, 0, stream>>>(w_init, wB0);
    cvt_lwT_kernel<<<(NCLS * HID + 255) / 256, 256, 0, stream>>>(lw[0], lwT[0], NCLS);
    cvt_lwT_kernel<<<(HID * HID + 255) / 256, 256, 0, stream>>>(lw[1], lwT[1], HID);
    cvt_lwT_kernel<<<(HID * HID + 255) / 256, 256, 0, stream>>>(lw[2], lwT[2], HID);

    const int mblocks = (N_NODES + 127) / 128;
    const int aggblocks = (N_NODES * 64 + 255) / 256;

    // h0s = (h @ w_init^T) * nsrc   [N,128] bf16
    {
        dim3 grid(NCLS / 128, mblocks);
        mfma_gemm<true, false><<<grid, 256, 0, stream>>>(h, wB0, h0s, N_NODES, FIN, NCLS,
                                                         nsrc, nullptr, nullptr);
    }

    // ---- layer 0 ----
    agg128<<<aggblocks, 256, 0, stream>>>(h0s, roff, csr, aggb);
    {
        dim3 grid(HID / 128, mblocks);
        mfma_gemm<false, true><<<grid, 256, 0, stream>>>(aggb, lwT[0], P[0], N_NODES, NCLS, HID,
                                                         ndst, lb[0], stats);
    }
    bnprep_kernel<<<1, 256, 0, stream>>>(stats, gamma[0], beta[0], bnab);

    // ---- layers 1,2 ----
    for (int l = 1; l < 3; l++) {
        ush* pin  = P[(l + 1) & 1];
        ush* pout = P[l & 1];
        agg256_bn<<<aggblocks, 256, 0, stream>>>(pin, bnab + (l - 1) * 2 * HID, nsrc,
                                                 roff, csr, aggb);
        dim3 grid(HID / 128, mblocks);
        mfma_gemm<false, true><<<grid, 256, 0, stream>>>(aggb, lwT[l], pout, N_NODES, HID, HID,
                                                         ndst, lb[l], stats + l * 2 * HID);
        bnprep_kernel<<<1, 256, 0, stream>>>(stats + l * 2 * HID, gamma[l], beta[l],
                                             bnab + l * 2 * HID);
    }

    // ---- readout ----
    {
        dim3 grid(N_GRAPHS, 8);
        segmax_bn<<<grid, 256, 0, stream>>>(P[0], bnab + 2 * 2 * HID, gst, hg);
    }
    fc_kernel<<<(N_GRAPHS * OUT_DIM + 255) / 256, 256, 0, stream>>>(hg, fc_w, fc_b, out);
}